// Round 1
// baseline (1365.269 us; speedup 1.0000x reference)
//
#include <hip/hip_runtime.h>

#define N_NODES  100000
#define N_EDGES  1600000
#define D_FEAT   64
#define N_GRAPHS 1000
#define D_MSG    30
#define D_H1     20
#define D_H2     10

// ---------------------------------------------------------------------------
// Kernel 1: per-edge message MLP + scatter-add to dst node accumulator.
// msg = relu(concat(x_src, x_dst, e_attr) @ W_msg + b_msg); x[dst] += msg
// One thread per edge; W_msg/b_msg addresses are wave-uniform -> s_load.
// Grid = exactly N_EDGES/256 blocks (no tail).
// ---------------------------------------------------------------------------
__global__ __launch_bounds__(256) void edge_msg_kernel(
    const int*   __restrict__ edge_index,   // [2][N_EDGES]
    const float* __restrict__ node_attr,    // [N_NODES][64]
    const float* __restrict__ edge_attr,    // [N_EDGES][64]
    const float* __restrict__ W_msg,        // [192][30]
    const float* __restrict__ b_msg,        // [30]
    float*       __restrict__ x)            // [N_NODES][30] (pre-zeroed)
{
    const int e = blockIdx.x * 256 + threadIdx.x;
    const int s = edge_index[e];
    const int d = edge_index[N_EDGES + e];

    float acc[D_MSG];
#pragma unroll
    for (int j = 0; j < D_MSG; ++j) acc[j] = b_msg[j];

    const float4* ps = (const float4*)(node_attr + (size_t)s * D_FEAT);
    const float4* pd = (const float4*)(node_attr + (size_t)d * D_FEAT);
    const float4* pe = (const float4*)(edge_attr + (size_t)e * D_FEAT);

    for (int seg = 0; seg < 3; ++seg) {
        const float4* p  = (seg == 0) ? ps : ((seg == 1) ? pd : pe);
        const float*  Ws = W_msg + seg * (D_FEAT * D_MSG);
#pragma unroll 4
        for (int q = 0; q < 16; ++q) {
            const float4 v  = p[q];
            const float* wr = Ws + q * 4 * D_MSG;
#pragma unroll
            for (int j = 0; j < D_MSG; ++j) acc[j] = fmaf(v.x, wr[j],           acc[j]);
#pragma unroll
            for (int j = 0; j < D_MSG; ++j) acc[j] = fmaf(v.y, wr[D_MSG + j],   acc[j]);
#pragma unroll
            for (int j = 0; j < D_MSG; ++j) acc[j] = fmaf(v.z, wr[2*D_MSG + j], acc[j]);
#pragma unroll
            for (int j = 0; j < D_MSG; ++j) acc[j] = fmaf(v.w, wr[3*D_MSG + j], acc[j]);
        }
    }

    float* xr = x + (size_t)d * D_MSG;
#pragma unroll
    for (int j = 0; j < D_MSG; ++j) {
        const float m = fmaxf(acc[j], 0.0f);
        if (m > 0.0f) atomicAdd(xr + j, m);   // relu'd message; skip zeros
    }
}

// ---------------------------------------------------------------------------
// Kernel 2: per-node head  h = relu(x @ W1 + b1), then pool into graph accum.
// ---------------------------------------------------------------------------
__global__ __launch_bounds__(256) void node_head_kernel(
    const float* __restrict__ x,       // [N_NODES][30]
    const int*   __restrict__ batch,   // [N_NODES]
    const float* __restrict__ W1,      // [30][20]
    const float* __restrict__ b1,      // [20]
    float*       __restrict__ g)       // [N_GRAPHS][20] (pre-zeroed)
{
    const int n = blockIdx.x * 256 + threadIdx.x;
    if (n >= N_NODES) return;

    float xv[D_MSG];
    const float2* px = (const float2*)(x + (size_t)n * D_MSG);  // 120B rows, 8B aligned
#pragma unroll
    for (int j = 0; j < D_MSG / 2; ++j) {
        const float2 t = px[j];
        xv[2*j] = t.x; xv[2*j+1] = t.y;
    }

    float h[D_H1];
#pragma unroll
    for (int t = 0; t < D_H1; ++t) h[t] = b1[t];
#pragma unroll
    for (int j = 0; j < D_MSG; ++j) {
#pragma unroll
        for (int t = 0; t < D_H1; ++t) h[t] = fmaf(xv[j], W1[j * D_H1 + t], h[t]);
    }

    const int gi = batch[n];
    float* gr = g + (size_t)gi * D_H1;
#pragma unroll
    for (int t = 0; t < D_H1; ++t) {
        const float hv = fmaxf(h[t], 0.0f);
        if (hv > 0.0f) atomicAdd(gr + t, hv);
    }
}

// ---------------------------------------------------------------------------
// Kernel 3: per-graph head  out = relu(g @ W2 + b2) @ W3 + b3
// ---------------------------------------------------------------------------
__global__ __launch_bounds__(256) void graph_head_kernel(
    const float* __restrict__ g,    // [N_GRAPHS][20]
    const float* __restrict__ W2,   // [20][10]
    const float* __restrict__ b2,   // [10]
    const float* __restrict__ W3,   // [10][1]
    const float* __restrict__ b3,   // [1]
    float*       __restrict__ out)  // [N_GRAPHS]
{
    const int i = blockIdx.x * 256 + threadIdx.x;
    if (i >= N_GRAPHS) return;

    float gv[D_H1];
    const float2* pg = (const float2*)(g + (size_t)i * D_H1);
#pragma unroll
    for (int j = 0; j < D_H1 / 2; ++j) {
        const float2 t = pg[j];
        gv[2*j] = t.x; gv[2*j+1] = t.y;
    }

    float h[D_H2];
#pragma unroll
    for (int t = 0; t < D_H2; ++t) h[t] = b2[t];
#pragma unroll
    for (int j = 0; j < D_H1; ++j) {
#pragma unroll
        for (int t = 0; t < D_H2; ++t) h[t] = fmaf(gv[j], W2[j * D_H2 + t], h[t]);
    }

    float o = b3[0];
#pragma unroll
    for (int t = 0; t < D_H2; ++t) o = fmaf(fmaxf(h[t], 0.0f), W3[t], o);

    out[i] = o;
}

// ---------------------------------------------------------------------------
extern "C" void kernel_launch(void* const* d_in, const int* in_sizes, int n_in,
                              void* d_out, int out_size, void* d_ws, size_t ws_size,
                              hipStream_t stream)
{
    const int*   edge_index = (const int*)  d_in[0];
    const float* node_attr  = (const float*)d_in[1];
    const float* edge_attr  = (const float*)d_in[2];
    const int*   batch      = (const int*)  d_in[3];
    const float* W_msg      = (const float*)d_in[4];
    const float* b_msg      = (const float*)d_in[5];
    const float* W1         = (const float*)d_in[6];
    const float* b1         = (const float*)d_in[7];
    const float* W2         = (const float*)d_in[8];
    const float* b2         = (const float*)d_in[9];
    const float* W3         = (const float*)d_in[10];
    const float* b3         = (const float*)d_in[11];

    float* x = (float*)d_ws;                          // [N_NODES][30]
    float* g = x + (size_t)N_NODES * D_MSG;           // [N_GRAPHS][20]

    const size_t zero_bytes =
        ((size_t)N_NODES * D_MSG + (size_t)N_GRAPHS * D_H1) * sizeof(float);
    hipMemsetAsync(d_ws, 0, zero_bytes, stream);

    edge_msg_kernel<<<N_EDGES / 256, 256, 0, stream>>>(
        edge_index, node_attr, edge_attr, W_msg, b_msg, x);

    node_head_kernel<<<(N_NODES + 255) / 256, 256, 0, stream>>>(
        x, batch, W1, b1, g);

    graph_head_kernel<<<(N_GRAPHS + 255) / 256, 256, 0, stream>>>(
        g, W2, b2, W3, b3, (float*)d_out);
}